// Round 2
// baseline (1849.271 us; speedup 1.0000x reference)
//
#include <hip/hip_runtime.h>
#include <math.h>

#define NFFT  512
#define WINL  320
#define HOP   160
#define FPAD  256
#define NF    257
#define TT    601
#define LSEQ  96000
#define XPLEN 96512
#define NCH   8
#define NB    8
#define NSEQ  64
#define NROWS 38464   // NSEQ*TT
#define DD    514
#define HH    128
#define G4    512
#define KPAD  544     // 17*32, zero-padded K for split-B arrays
#define NCOMB 1026    // 514 (S cols) + 512 (XW cols)
#define CHPB  16      // chains per LSTM block

typedef _Float16 h2v __attribute__((ext_vector_type(2)));
typedef short bf16x8 __attribute__((ext_vector_type(8)));
typedef float f32x4 __attribute__((ext_vector_type(4)));

// ---------------- init helpers ----------------
__device__ __forceinline__ float winval(int k) {
  if (k < 96 || k >= 416) return 0.f;
  return 0.5f - 0.5f * cosf((float)(2.0 * M_PI / 320.0) * (float)(k - 96));
}

__device__ __forceinline__ void split_bf16(float v, unsigned short* h, unsigned short* l) {
  unsigned int hb = __float_as_uint(v) >> 16;
  float r = v - __uint_as_float(hb << 16);
  *h = (unsigned short)hb;
  *l = (unsigned short)(__float_as_uint(r) >> 16);
}

__global__ void k_wsq(float* __restrict__ wsq) {
  int p = blockIdx.x * 256 + threadIdx.x;
  if (p >= XPLEN) return;
  int t0 = (p <= 511) ? 0 : (p - 352) / 160;
  int t1 = p / 160; if (t1 > 600) t1 = 600;
  float s = 0.f;
  for (int t = t0; t <= t1; t++) { float w = winval(p - t * HOP); s += w * w; }
  wsq[p] = s;
}

// fp32 forward-DFT matrix BFf[k][d] (512 x 514), for the BW precompute GEMM
__global__ void k_bff(float* __restrict__ BFf) {
  int idx = blockIdx.x * 256 + threadIdx.x;
  if (idx >= NFFT * DD) return;
  int k = idx / DD, d = idx - k * DD;
  float w = winval(k);
  int f = (d < NF) ? d : d - NF;
  int m = (k * f) & 511;
  float th = (float)(M_PI / 256.0) * (float)m;
  BFf[idx] = ((d < NF) ? cosf(th) : -sinf(th)) * w;
}

// WT split: Bt[n][k] = Wih[n][k]  (used by the BW precompute)
__global__ void k_wtsplit(const float* __restrict__ Wih, unsigned short* __restrict__ H,
                          unsigned short* __restrict__ L) {
  int idx = blockIdx.x * 256 + threadIdx.x;
  if (idx >= G4 * KPAD) return;
  int n = idx / KPAD, k = idx - n * KPAD;
  float v = (k < DD) ? Wih[n * DD + k] : 0.f;
  split_bf16(v, &H[idx], &L[idx]);
}

// Combined split B for the fused STFT+xW GEMM: BC[n][k], n in [0,1152)
__global__ void k_bcomb(const float* __restrict__ BWf, unsigned short* __restrict__ H,
                        unsigned short* __restrict__ L) {
  int idx = blockIdx.x * 256 + threadIdx.x;
  if (idx >= 1152 * KPAD) return;
  int n = idx / KPAD, k = idx - n * KPAD;
  float v = 0.f;
  if (k < NFFT) {
    if (n < DD) {
      float w = winval(k);
      int f = (n < NF) ? n : n - NF;
      int m = (k * f) & 511;
      float th = (float)(M_PI / 256.0) * (float)m;
      v = ((n < NF) ? cosf(th) : -sinf(th)) * w;
    } else if (n < NCOMB) {
      v = BWf[k * G4 + (n - 514)];
    }
  }
  split_bf16(v, &H[idx], &L[idx]);
}

// BI split: Bt[n][kk] = BI[kk][n]
__global__ void k_bisplit(unsigned short* __restrict__ H, unsigned short* __restrict__ L) {
  int idx = blockIdx.x * 256 + threadIdx.x;
  if (idx >= NFFT * KPAD) return;
  int n = idx / KPAD, kk = idx - n * KPAD;
  float v = 0.f;
  if (kk < DD) {
    float w = winval(n);
    int f = (kk < NF) ? kk : kk - NF;
    int edge = (f == 0 || f == 256);
    float alpha = edge ? 1.f : 2.f;
    int m = (n * f) & 511;
    float th = (float)(M_PI / 256.0) * (float)m;
    float c;
    if (kk < NF) c = alpha * cosf(th);
    else         c = edge ? 0.f : -alpha * sinf(th);
    v = c * w * (1.f / 512.f);
  }
  split_bf16(v, &H[idx], &L[idx]);
}

__global__ void k_bsum(const float* __restrict__ bih, const float* __restrict__ bhh,
                       float* __restrict__ BSUM) {
  int idx = blockIdx.x * 256 + threadIdx.x;
  if (idx < G4) BSUM[idx] = bih[idx] + bhh[idx];
}

// W1/W2 mask-weight split: Ws[n'][k], n' = ri*320 + f
__global__ void k_wmsplit(const float* __restrict__ W1, const float* __restrict__ W2,
                          unsigned short* __restrict__ W1h, unsigned short* __restrict__ W1l,
                          unsigned short* __restrict__ W2h, unsigned short* __restrict__ W2l) {
  int idx = blockIdx.x * 256 + threadIdx.x;
  if (idx >= 2 * 640 * HH) return;
  int m = idx / (640 * HH);
  int rem = idx - m * 640 * HH;
  int np = rem / HH, k = rem - np * HH;
  int ri = np / 320, f = np - ri * 320;
  float v = 0.f;
  if (f < NF) {
    int fcol = (ri == 0) ? f : NF + f;
    v = (m == 0) ? W1[fcol * HH + k] : W2[fcol * HH + k];
  }
  unsigned short h, l;
  split_bf16(v, &h, &l);
  if (m == 0) { W1h[rem] = h; W1l[rem] = l; }
  else        { W2h[rem] = h; W2l[rem] = l; }
}

// Whh -> MFMA B-fragments, split-bf16 hi/lo.
// Fragment for (wave w, lane l, class c, chunk q): value = Whh[c*128 + 16w + (l&15)][q*32 + (l>>4)*8 + r]
// Flat ush index: ((((w*64+l)*4 + c)*4 + q)*2 + half)*8 + r   (per-lane 256 ush = 32 uint4)
__global__ void k_wfrag(const float* __restrict__ Whh, unsigned short* __restrict__ WF) {
  int idx = blockIdx.x * 256 + threadIdx.x;   // (w,l,c,q,r) = 8*64*4*4*8 = 131072
  if (idx >= 131072) return;
  int r = idx & 7;
  int q = (idx >> 3) & 3;
  int c = (idx >> 5) & 3;
  int l = (idx >> 7) & 63;
  int w = idx >> 13;
  int row = c * 128 + 16 * w + (l & 15);
  int col = q * 32 + (l >> 4) * 8 + r;
  float v = Whh[row * HH + col];
  unsigned short hb, lb;
  split_bf16(v, &hb, &lb);
  long base = ((((long)(w * 64 + l) * 4 + c) * 4 + q) * 2) * 8 + r;
  WF[base] = hb;       // hi half
  WF[base + 8] = lb;   // lo half
}

// reflect-padded multichannel extraction, pre-split to bf16 hi/lo: XPh/XPl[n][i]
__global__ void k_xp(const float* __restrict__ x, unsigned short* __restrict__ XPh,
                     unsigned short* __restrict__ XPl) {
  int idx = blockIdx.x * 256 + threadIdx.x;
  if (idx >= NSEQ * XPLEN) return;
  int n = idx / XPLEN, i = idx - n * XPLEN;
  int j = i - FPAD;
  if (j < 0) j = -j;
  else if (j >= LSEQ) j = 2 * LSEQ - 2 - j;
  int b = n >> 3, c = n & 7;
  float v = x[((long)b * LSEQ + j) * NCH + c];
  split_bf16(v, &XPh[idx], &XPl[idx]);
}

// ---------------- split-bf16 MFMA GEMM (fp32 A): C[M,N] = A[M,K] * Bt^T (+bias) ----------------
template <int GATHER>
__launch_bounds__(256)
__global__ void k_gemm3(const float* __restrict__ A,
                        const unsigned short* __restrict__ Bth,
                        const unsigned short* __restrict__ Btl,
                        const float* __restrict__ bias, float* __restrict__ C,
                        int M, int N, int K, int lda, int ldc) {
  __shared__ __align__(16) unsigned short sAh[128 * 40];
  __shared__ __align__(16) unsigned short sAl[128 * 40];
  __shared__ __align__(16) unsigned short sBh[128 * 40];
  __shared__ __align__(16) unsigned short sBl[128 * 40];
  const int tid = threadIdx.x;
  const int row0 = blockIdx.y * 128, col0 = blockIdx.x * 128;
  const int sar = tid >> 1, sak = (tid & 1) * 16;
  const int arow = row0 + sar;
  long abase = (long)arow * lda;
  const bool arok = (arow < M);
  const int lane = tid & 63, w = tid >> 6;
  const int wm = (w >> 1) * 64, wn = (w & 1) * 64;
  const int l15 = lane & 15, quad = lane >> 4;
  f32x4 acc[4][4] = {};
  unsigned int* aH = (unsigned int*)sAh;
  unsigned int* aL = (unsigned int*)sAl;
  uint4* bH = (uint4*)sBh;
  uint4* bL = (uint4*)sBl;
  for (int k0 = 0; k0 < K; k0 += 32) {
#pragma unroll
    for (int i = 0; i < 8; i++) {
      int kk = k0 + sak + 2 * i;
      float v0 = 0.f, v1 = 0.f;
      if (arok) {
        if (kk + 1 < K) { float2 t2 = *(const float2*)(A + abase + kk); v0 = t2.x; v1 = t2.y; }
        else if (kk < K) { v0 = A[abase + kk]; }
      }
      unsigned int h0 = __float_as_uint(v0) >> 16, h1 = __float_as_uint(v1) >> 16;
      float r0 = v0 - __uint_as_float(h0 << 16), r1 = v1 - __uint_as_float(h1 << 16);
      unsigned int l0 = __float_as_uint(r0) >> 16, l1 = __float_as_uint(r1) >> 16;
      aH[sar * 20 + (sak >> 1) + i] = h0 | (h1 << 16);
      aL[sar * 20 + (sak >> 1) + i] = l0 | (l1 << 16);
    }
#pragma unroll
    for (int h = 0; h < 2; h++) {
      int idx = tid + h * 256;
      int r = idx >> 2, c = idx & 3;
      long go = (long)(col0 + r) * KPAD + k0 + c * 8;
      bH[r * 5 + c] = *(const uint4*)(Bth + go);
      bL[r * 5 + c] = *(const uint4*)(Btl + go);
    }
    __syncthreads();
    bf16x8 ah[4], al[4], bh[4], bl[4];
#pragma unroll
    for (int i = 0; i < 4; i++) {
      int off = (wm + i * 16 + l15) * 40 + quad * 8;
      ah[i] = *(const bf16x8*)(sAh + off);
      al[i] = *(const bf16x8*)(sAl + off);
      int boff = (wn + i * 16 + l15) * 40 + quad * 8;
      bh[i] = *(const bf16x8*)(sBh + boff);
      bl[i] = *(const bf16x8*)(sBl + boff);
    }
#pragma unroll
    for (int i = 0; i < 4; i++)
#pragma unroll
      for (int j = 0; j < 4; j++) {
        acc[i][j] = __builtin_amdgcn_mfma_f32_16x16x32_bf16(al[i], bh[j], acc[i][j], 0, 0, 0);
        acc[i][j] = __builtin_amdgcn_mfma_f32_16x16x32_bf16(ah[i], bl[j], acc[i][j], 0, 0, 0);
        acc[i][j] = __builtin_amdgcn_mfma_f32_16x16x32_bf16(ah[i], bh[j], acc[i][j], 0, 0, 0);
      }
    __syncthreads();
  }
#pragma unroll
  for (int i = 0; i < 4; i++)
#pragma unroll
    for (int j = 0; j < 4; j++) {
      int cc = col0 + wn + j * 16 + l15;
      if (cc >= N) continue;
      float bv = bias ? bias[cc] : 0.f;
#pragma unroll
      for (int rg = 0; rg < 4; rg++) {
        int rr = row0 + wm + i * 16 + quad * 4 + rg;
        if (rr < M) C[(long)rr * ldc + cc] = acc[i][j][rg] + bv;
      }
    }
}

// ---------------- fused STFT+xW GEMM: pre-split A (gathered XP), combined B ----------------
// C[38464, 1026]: cols <514 -> S; cols 514..1025 -> XW (+bsum). K=512, tile 128x128.
// XW columns stored PERMUTED: gate jj = c*128+e -> slot e*4+c (element-major, class-minor).
__launch_bounds__(256)
__global__ void k_gemm4(const unsigned short* __restrict__ Ah, const unsigned short* __restrict__ Al,
                        const unsigned short* __restrict__ Bh, const unsigned short* __restrict__ Bl,
                        const float* __restrict__ bsum, float* __restrict__ S,
                        float* __restrict__ XW) {
  __shared__ __align__(16) unsigned short sAh[128 * 40];
  __shared__ __align__(16) unsigned short sAl[128 * 40];
  __shared__ __align__(16) unsigned short sBh[128 * 40];
  __shared__ __align__(16) unsigned short sBl[128 * 40];
  const int tid = threadIdx.x;
  const int row0 = blockIdx.y * 128, col0 = blockIdx.x * 128;
  const int sr0 = tid >> 2, c4 = (tid & 3) * 8, cq = tid & 3;
  long ab0, ab1;
  { int rr = row0 + sr0;      int n = rr / TT, t = rr - n * TT; ab0 = (long)n * XPLEN + (long)t * HOP; }
  { int rr = row0 + sr0 + 64; int n = rr / TT, t = rr - n * TT; ab1 = (long)n * XPLEN + (long)t * HOP; }
  const int lane = tid & 63, w = tid >> 6;
  const int wm = (w >> 1) * 64, wn = (w & 1) * 64;
  const int l15 = lane & 15, quad = lane >> 4;
  f32x4 acc[4][4] = {};
  uint4* aH4 = (uint4*)sAh; uint4* aL4 = (uint4*)sAl;
  uint4* bH4 = (uint4*)sBh; uint4* bL4 = (uint4*)sBl;
  for (int k0 = 0; k0 < NFFT; k0 += 32) {
    aH4[sr0 * 5 + cq]        = *(const uint4*)(Ah + ab0 + k0 + c4);
    aL4[sr0 * 5 + cq]        = *(const uint4*)(Al + ab0 + k0 + c4);
    aH4[(sr0 + 64) * 5 + cq] = *(const uint4*)(Ah + ab1 + k0 + c4);
    aL4[(sr0 + 64) * 5 + cq] = *(const uint4*)(Al + ab1 + k0 + c4);
    {
      long go = (long)(col0 + sr0) * KPAD + k0 + c4;
      bH4[sr0 * 5 + cq] = *(const uint4*)(Bh + go);
      bL4[sr0 * 5 + cq] = *(const uint4*)(Bl + go);
      go = (long)(col0 + sr0 + 64) * KPAD + k0 + c4;
      bH4[(sr0 + 64) * 5 + cq] = *(const uint4*)(Bh + go);
      bL4[(sr0 + 64) * 5 + cq] = *(const uint4*)(Bl + go);
    }
    __syncthreads();
    bf16x8 ah[4], al[4], bh[4], bl[4];
#pragma unroll
    for (int i = 0; i < 4; i++) {
      int off = (wm + i * 16 + l15) * 40 + quad * 8;
      ah[i] = *(const bf16x8*)(sAh + off);
      al[i] = *(const bf16x8*)(sAl + off);
      int boff = (wn + i * 16 + l15) * 40 + quad * 8;
      bh[i] = *(const bf16x8*)(sBh + boff);
      bl[i] = *(const bf16x8*)(sBl + boff);
    }
#pragma unroll
    for (int i = 0; i < 4; i++)
#pragma unroll
      for (int j = 0; j < 4; j++) {
        acc[i][j] = __builtin_amdgcn_mfma_f32_16x16x32_bf16(al[i], bh[j], acc[i][j], 0, 0, 0);
        acc[i][j] = __builtin_amdgcn_mfma_f32_16x16x32_bf16(ah[i], bl[j], acc[i][j], 0, 0, 0);
        acc[i][j] = __builtin_amdgcn_mfma_f32_16x16x32_bf16(ah[i], bh[j], acc[i][j], 0, 0, 0);
      }
    __syncthreads();
  }
#pragma unroll
  for (int i = 0; i < 4; i++)
#pragma unroll
    for (int j = 0; j < 4; j++) {
      int cc = col0 + wn + j * 16 + l15;
      if (cc >= NCOMB) continue;
#pragma unroll
      for (int rg = 0; rg < 4; rg++) {
        int rr = row0 + wm + i * 16 + quad * 4 + rg;
        if (rr >= NROWS) continue;
        float v = acc[i][j][rg];
        if (cc < DD) S[(long)rr * DD + cc] = v;
        else {
          int jj = cc - DD;
          XW[(long)rr * G4 + (((jj & 127) << 2) | (jj >> 7))] = v + bsum[jj];
        }
      }
    }
}

// ---------------- iSTFT GEMM: pre-split A (pitch KPAD), B = BI split ----------------
__launch_bounds__(256)
__global__ void k_gemm5(const unsigned short* __restrict__ Ah, const unsigned short* __restrict__ Al,
                        const unsigned short* __restrict__ Bh, const unsigned short* __restrict__ Bl,
                        float* __restrict__ C, int M, int N, int ldc) {
  __shared__ __align__(16) unsigned short sAh[128 * 40];
  __shared__ __align__(16) unsigned short sAl[128 * 40];
  __shared__ __align__(16) unsigned short sBh[128 * 40];
  __shared__ __align__(16) unsigned short sBl[128 * 40];
  const int tid = threadIdx.x;
  const int row0 = blockIdx.y * 128, col0 = blockIdx.x * 128;
  const int sr0 = tid >> 2, c4 = (tid & 3) * 8, cq = tid & 3;
  const int lane = tid & 63, w = tid >> 6;
  const int wm = (w >> 1) * 64, wn = (w & 1) * 64;
  const int l15 = lane & 15, quad = lane >> 4;
  f32x4 acc[4][4] = {};
  uint4* aH4 = (uint4*)sAh; uint4* aL4 = (uint4*)sAl;
  uint4* bH4 = (uint4*)sBh; uint4* bL4 = (uint4*)sBl;
  for (int k0 = 0; k0 < KPAD; k0 += 32) {
    {
      long go = (long)(row0 + sr0) * KPAD + k0 + c4;
      aH4[sr0 * 5 + cq] = *(const uint4*)(Ah + go);
      aL4[sr0 * 5 + cq] = *(const uint4*)(Al + go);
      go = (long)(row0 + sr0 + 64) * KPAD + k0 + c4;
      aH4[(sr0 + 64) * 5 + cq] = *(const uint4*)(Ah + go);
      aL4[(sr0 + 64) * 5 + cq] = *(const uint4*)(Al + go);
    }
    {
      long go = (long)(col0 + sr0) * KPAD + k0 + c4;
      bH4[sr0 * 5 + cq] = *(const uint4*)(Bh + go);
      bL4[sr0 * 5 + cq] = *(const uint4*)(Bl + go);
      go = (long)(col0 + sr0 + 64) * KPAD + k0 + c4;
      bH4[(sr0 + 64) * 5 + cq] = *(const uint4*)(Bh + go);
      bL4[(sr0 + 64) * 5 + cq] = *(const uint4*)(Bl + go);
    }
    __syncthreads();
    bf16x8 ah[4], al[4], bh[4], bl[4];
#pragma unroll
    for (int i = 0; i < 4; i++) {
      int off = (wm + i * 16 + l15) * 40 + quad * 8;
      ah[i] = *(const bf16x8*)(sAh + off);
      al[i] = *(const bf16x8*)(sAl + off);
      int boff = (wn + i * 16 + l15) * 40 + quad * 8;
      bh[i] = *(const bf16x8*)(sBh + boff);
      bl[i] = *(const bf16x8*)(sBl + boff);
    }
#pragma unroll
    for (int i = 0; i < 4; i++)
#pragma unroll
      for (int j = 0; j < 4; j++) {
        acc[i][j] = __builtin_amdgcn_mfma_f32_16x16x32_bf16(al[i], bh[j], acc[i][j], 0, 0, 0);
        acc[i][j] = __builtin_amdgcn_mfma_f32_16x16x32_bf16(ah[i], bl[j], acc[i][j], 0, 0, 0);
        acc[i][j] = __builtin_amdgcn_mfma_f32_16x16x32_bf16(ah[i], bh[j], acc[i][j], 0, 0, 0);
      }
    __syncthreads();
  }
#pragma unroll
  for (int i = 0; i < 4; i++)
#pragma unroll
    for (int j = 0; j < 4; j++) {
      int cc = col0 + wn + j * 16 + l15;
      if (cc >= N) continue;
#pragma unroll
      for (int rg = 0; rg < 4; rg++) {
        int rr = row0 + wm + i * 16 + quad * 4 + rg;
        if (rr < M) C[(long)rr * ldc + cc] = acc[i][j][rg];
      }
    }
}

// ---------------- LSTM v10: batched-MFMA recurrence, 4 blocks x 16 chains ----------------
// Per step: G[16 chains][512 gates] = H[16][128] @ Whh^T via split-bf16 mfma_16x16x32
// (3 mfma per product, as in all GEMMs here). Wave w owns elements [16w,16w+16);
// its 4 N-tiles are the i/f/g/o class-tiles of those elements, so all 4 gates of a
// (chain, element) land in one lane's acc regs (chain = quad*4+reg, element = 16w+(lane&15)).
// acc is initialized from XW (slot = e*4+c, produced by k_gemm4), fusing the xW add.
// h carried as split-bf16 hi/lo in double-buffered LDS; one barrier/step.
__launch_bounds__(512)
__global__ void k_lstm(const float* __restrict__ XW, const unsigned short* __restrict__ WF,
                       float* __restrict__ Hout) {
  __shared__ __align__(16) unsigned short hhb[2][16][136];
  __shared__ __align__(16) unsigned short hlb[2][16][136];
  const int tid = threadIdx.x;
  const int blk = blockIdx.x;
  const int w = tid >> 6, lane = tid & 63;
  const int l15 = lane & 15, quad = lane >> 4;
  // preload Whh fragments (static, 32 uint4 = 128 VGPR)
  bf16x8 bw[4][4][2];
  {
    const uint4* wf4 = (const uint4*)(WF + (long)(w * 64 + lane) * 256);
#pragma unroll
    for (int c = 0; c < 4; c++)
#pragma unroll
      for (int q = 0; q < 4; q++)
#pragma unroll
        for (int h = 0; h < 2; h++)
          bw[c][q][h] = __builtin_bit_cast(bf16x8, wf4[(c * 4 + q) * 2 + h]);
  }
  // zero h buffer 0
  {
    unsigned short* z0 = &hhb[0][0][0];
    unsigned short* z1 = &hlb[0][0][0];
    for (int i = tid; i < 16 * 136; i += 512) { z0[i] = 0; z1[i] = 0; }
  }
  const int e = 16 * w + l15;
  long xbase[4];
  float* hbase[4];
#pragma unroll
  for (int r = 0; r < 4; r++) {
    int n = blk * CHPB + quad * 4 + r;
    xbase[r] = (long)n * TT * G4 + e * 4;
    hbase[r] = Hout + (long)n * TT * HH + e;
  }
  f32x4 xwn[4];
#pragma unroll
  for (int r = 0; r < 4; r++) xwn[r] = *(const f32x4*)(XW + xbase[r]);
  float cst[4] = {0.f, 0.f, 0.f, 0.f};
  __syncthreads();
  for (int t = 0; t < TT; t++) {
    const int cur = t & 1, nxt = cur ^ 1;
    f32x4 xwc[4];
#pragma unroll
    for (int r = 0; r < 4; r++) xwc[r] = xwn[r];
    if (t + 1 < TT) {
#pragma unroll
      for (int r = 0; r < 4; r++) xwn[r] = *(const f32x4*)(XW + xbase[r] + (long)(t + 1) * G4);
    }
    f32x4 acc[4];
#pragma unroll
    for (int c = 0; c < 4; c++) {
      f32x4 a; a[0] = xwc[0][c]; a[1] = xwc[1][c]; a[2] = xwc[2][c]; a[3] = xwc[3][c];
      acc[c] = a;
    }
#pragma unroll
    for (int q = 0; q < 4; q++) {
      const int ko = q * 32 + quad * 8;
      bf16x8 a_h = *(const bf16x8*)&hhb[cur][l15][ko];
      bf16x8 a_l = *(const bf16x8*)&hlb[cur][l15][ko];
#pragma unroll
      for (int c = 0; c < 4; c++) {
        acc[c] = __builtin_amdgcn_mfma_f32_16x16x32_bf16(a_l, bw[c][q][0], acc[c], 0, 0, 0);
        acc[c] = __builtin_amdgcn_mfma_f32_16x16x32_bf16(a_h, bw[c][q][1], acc[c], 0, 0, 0);
        acc[c] = __builtin_amdgcn_mfma_f32_16x16x32_bf16(a_h, bw[c][q][0], acc[c], 0, 0, 0);
      }
    }
#pragma unroll
    for (int r = 0; r < 4; r++) {
      float gi = acc[0][r], gf = acc[1][r], gg = acc[2][r], go = acc[3][r];
      // sig(i)*tanh(g) = (eg-1)/((1+ei)(1+eg)); sig(f)*c = c/(1+ef); clamp keeps eg/ec finite
      float ei = __expf(-gi);
      float ef = __expf(-gf);
      float eo = __expf(-go);
      float ggc = fminf(fmaxf(gg, -20.f), 20.f);
      float eg = __expf(2.f * ggc);
      float u = 1.f / ((1.f + ei) * (1.f + eg));
      float v = 1.f / (1.f + ef);
      float c2 = cst[r] * v + (eg - 1.f) * u;
      cst[r] = c2;
      float cc = fminf(fmaxf(c2, -20.f), 20.f);
      float ec = __expf(2.f * cc);
      float w2 = 1.f / ((1.f + eo) * (1.f + ec));
      float hv = (ec - 1.f) * w2;
      unsigned short hb, lb;
      split_bf16(hv, &hb, &lb);
      hhb[nxt][quad * 4 + r][e] = hb;
      hlb[nxt][quad * 4 + r][e] = lb;
      hbase[r][(long)t * HH] = hv;
    }
    __syncthreads();
  }
}

// ---------------- mask GEMM (split-bf16 MFMA) + mask apply + transpose ----------------
// MS layout: [b][f][c][t] complex-interleaved (re,im)
__launch_bounds__(256)
__global__ void k_maskms(const float* __restrict__ Hout,
                         const unsigned short* __restrict__ Wsh,
                         const unsigned short* __restrict__ Wsl,
                         const float* __restrict__ bias, const float* __restrict__ S,
                         float* __restrict__ MS) {
  __shared__ __align__(16) unsigned short sAh[64 * 40];
  __shared__ __align__(16) unsigned short sAl[64 * 40];
  __shared__ __align__(16) unsigned short sBh[64 * 40];
  __shared__ __align__(16) unsigned short sBl[64 * 40];
  __shared__ float Cs[64][68];
  __shared__ float SR[64][33];
  __shared__ float SI[64][33];
  const int tid = threadIdx.x;
  const int f0 = blockIdx.x * 32;
  const int row0 = blockIdx.y * 64;
  const int lane = tid & 63, w = tid >> 6;
  const int wm = w * 16;
  const int l15 = lane & 15, quad = lane >> 4;
  const int sar = tid >> 2;
  const int sak = (tid & 3) * 8;
  const int np = ((sar < 32) ? 0 : 320 - 32) + f0 + sar;
  unsigned int* aH = (unsigned int*)sAh;
  unsigned int* aL = (unsigned int*)sAl;
  f32x4 acc[4] = {};
  for (int k0 = 0; k0 < HH; k0 += 32) {
    {
      const float* ap = Hout + (long)(row0 + sar) * HH + k0 + sak;
      float4 v0 = *(const float4*)ap;
      float4 v1 = *(const float4*)(ap + 4);
      float vv[8] = {v0.x, v0.y, v0.z, v0.w, v1.x, v1.y, v1.z, v1.w};
#pragma unroll
      for (int i = 0; i < 4; i++) {
        unsigned int h0 = __float_as_uint(vv[2 * i]) >> 16, h1 = __float_as_uint(vv[2 * i + 1]) >> 16;
        float r0 = vv[2 * i] - __uint_as_float(h0 << 16), r1 = vv[2 * i + 1] - __uint_as_float(h1 << 16);
        unsigned int l0 = __float_as_uint(r0) >> 16, l1 = __float_as_uint(r1) >> 16;
        aH[sar * 20 + (sak >> 1) + i] = h0 | (h1 << 16);
        aL[sar * 20 + (sak >> 1) + i] = l0 | (l1 << 16);
      }
    }
    {
      long go = (long)np * HH + k0 + sak;
      *(uint4*)(sBh + sar * 40 + sak) = *(const uint4*)(Wsh + go);
      *(uint4*)(sBl + sar * 40 + sak) = *(const uint4*)(Wsl + go);
    }
    __syncthreads();
    bf16x8 ah = *(const bf16x8*)(sAh + (wm + l15) * 40 + quad * 8);
    bf16x8 al = *(const bf16x8*)(sAl + (wm + l15) * 40 + quad * 8);
#pragma unroll
    for (int ct = 0; ct < 4; ct++) {
      bf16x8 bh = *(const bf16x8*)(sBh + (ct * 16 + l15) * 40 + quad * 8);
      bf16x8 bl = *(const bf16x8*)(sBl + (ct * 16 + l15) * 40 + quad * 8);
      acc[ct] = __builtin_amdgcn_mfma_f32_16x16x32_bf16(al, bh, acc[ct], 0, 0, 0);
      acc[ct] = __builtin_amdgcn_mfma_f32_16x16x32_bf16(ah, bl, acc[ct], 0, 0, 0);
      acc[ct] = __builtin_amdgcn_mfma_f32_16x16x32_bf16(ah, bh, acc[ct], 0, 0, 0);
    }
    __syncthreads();
  }
#pragma unroll
  for (int ct = 0; ct < 4; ct++) {
    int col = ct * 16 + l15;
    int f = f0 + (col & 31);
    int fcol = (col < 32) ? f : NF + f;
    float bv = (f < NF) ? bias[fcol] : 0.f;
#pragma unroll
    for (int rg = 0; rg < 4; rg++) Cs[wm + quad * 4 + rg][col] = acc[ct][rg] + bv;
  }
  __syncthreads();
  {
    int fl = tid & 31, r8 = tid >> 5;
    int f = f0 + fl;
#pragma unroll
    for (int i = 0; i < 8; i++) {
      int rl = r8 * 8 + i;
      int rr = row0 + rl;
      float rm = Cs[rl][fl], im = Cs[rl][32 + fl];
      float sr = 0.f, si = 0.f;
      if (f < NF) { sr = S[(long)rr * DD + f]; si = S[(long)rr * DD + NF + f]; }
      SR[rl][fl] = rm * sr - im * si;
      SI[rl][fl] = rm * si + im * sr;
    }
  }
  __syncthreads();
  {
    int tl = tid & 63, fq = tid >> 6;
    int rr = row0 + tl;
    int n = rr / TT, t = rr - n * TT;
    int b = n >> 3, c = n & 7;
#pragma unroll
    for (int i = 0; i < 8; i++) {
      int fl = fq * 8 + i;
      int f = f0 + fl;
      if (f < NF) {
        long addr = ((((long)b * NF + f) * 8 + c) * (long)TT + t) * 2;
        *(float2*)&MS[addr] = make_float2(SR[tl][fl], SI[tl][fl]);
      }
    }
  }
}

// ---------------- PSD: one block per (b,f); complex-interleaved MS ----------------
__launch_bounds__(256)
__global__ void k_psd(const float* __restrict__ MS, float* __restrict__ PSD) {
  __shared__ float buf[9616];
  __shared__ float part[64][8];
  const int tid = threadIdx.x;
  const long base = (long)blockIdx.x * 9616;
  for (int i = tid; i < 9616; i += 256) buf[i] = MS[base + i];
  __syncthreads();
  int p = tid & 63, q = tid >> 6;
  int c = p >> 3, e = p & 7;
  const float2* xc = (const float2*)&buf[c * 1202];
  const float2* xe = (const float2*)&buf[e * 1202];
  int t0 = q * 150, t1 = (q == 3) ? TT : t0 + 150;
  float ar = 0.f, ai = 0.f;
  for (int t = t0; t < t1; t++) {
    float2 m = xc[t];
    float2 v = xe[t];
    ar += m.x * v.x + m.y * v.y;
    ai += m.y * v.x - m.x * v.y;
  }
  part[p][q * 2] = ar; part[p][q * 2 + 1] = ai;
  __syncthreads();
  if (tid < 64) {
    float sr = part[tid][0] + part[tid][2] + part[tid][4] + part[tid][6];
    float si = part[tid][1] + part[tid][3] + part[tid][5] + part[tid][7];
    PSD[((long)blockIdx.x * 64 + tid) * 2]     = sr * (1.f / 601.f);
    PSD[((long)blockIdx.x * 64 + tid) * 2 + 1] = si * (1.f / 601.f);
  }
}

// ---------------- 8x8 complex solve + MVDR weight ----------------
__launch_bounds__(64)
__global__ void k_solve(const float* __restrict__ PS, const float* __restrict__ PN,
                        float* __restrict__ WV) {
  int idx = blockIdx.x * 64 + threadIdx.x;
  if (idx >= NB * NF) return;
  float Ar[8][8], Ai[8][8], Br[8][8], Bi[8][8];
  const float* pn = PN + (long)idx * 128;
  const float* ps = PS + (long)idx * 128;
  for (int i = 0; i < 8; i++)
    for (int j = 0; j < 8; j++) {
      Ar[i][j] = pn[(i * 8 + j) * 2]; Ai[i][j] = pn[(i * 8 + j) * 2 + 1];
      Br[i][j] = ps[(i * 8 + j) * 2]; Bi[i][j] = ps[(i * 8 + j) * 2 + 1];
    }
  float tr = 0.f;
  for (int i = 0; i < 8; i++) tr += Ar[i][i];
  float load = 1e-6f * tr / 8.f + 1e-8f;
  for (int i = 0; i < 8; i++) Ar[i][i] += load;
  for (int k = 0; k < 8; k++) {
    int piv = k; float mx = Ar[k][k] * Ar[k][k] + Ai[k][k] * Ai[k][k];
    for (int i = k + 1; i < 8; i++) {
      float m2 = Ar[i][k] * Ar[i][k] + Ai[i][k] * Ai[i][k];
      if (m2 > mx) { mx = m2; piv = i; }
    }
    if (piv != k) {
      for (int j = 0; j < 8; j++) {
        float t0;
        t0 = Ar[k][j]; Ar[k][j] = Ar[piv][j]; Ar[piv][j] = t0;
        t0 = Ai[k][j]; Ai[k][j] = Ai[piv][j]; Ai[piv][j] = t0;
        t0 = Br[k][j]; Br[k][j] = Br[piv][j]; Br[piv][j] = t0;
        t0 = Bi[k][j]; Bi[k][j] = Bi[piv][j]; Bi[piv][j] = t0;
      }
    }
    float dr = Ar[k][k], di = Ai[k][k];
    float inv = 1.f / (dr * dr + di * di);
    float irr = dr * inv, iii = -di * inv;
    for (int j = 0; j < 8; j++) {
      float xr = Ar[k][j], xi = Ai[k][j];
      Ar[k][j] = xr * irr - xi * iii; Ai[k][j] = xr * iii + xi * irr;
      xr = Br[k][j]; xi = Bi[k][j];
      Br[k][j] = xr * irr - xi * iii; Bi[k][j] = xr * iii + xi * irr;
    }
    for (int i = 0; i < 8; i++) {
      if (i == k) continue;
      float fr = Ar[i][k], fi = Ai[i][k];
      for (int j = 0; j < 8; j++) {
        float kr = Ar[k][j], ki = Ai[k][j];
        Ar[i][j] -= fr * kr - fi * ki;
        Ai[i][j] -= fr * ki + fi * kr;
        kr = Br[k][j]; ki = Bi[k][j];
        Br[i][j] -= fr * kr - fi * ki;
        Bi[i][j] -= fr * ki + fi * kr;
      }
    }
  }
  float trr = 1e-8f, tri = 0.f;
  for (int i = 0; i < 8; i++) { trr += Br[i][i]; tri += Bi[i][i]; }
  float inv = 1.f / (trr * trr + tri * tri);
  for (int c = 0; c < 8; c++) {
    float xr = Br[c][0], xi = Bi[c][0];
    WV[((long)idx * 8 + c) * 2]     = (xr * trr + xi * tri) * inv;
    WV[((long)idx * 8 + c) * 2 + 1] = (xi * trr - xr * tri) * inv;
  }
}

// ---------------- beamform -> pre-split ENH (KPAD rows) ----------------
__launch_bounds__(320)
__global__ void k_beam(const float* __restrict__ S, const float* __restrict__ WV,
                       unsigned short* __restrict__ ENHh, unsigned short* __restrict__ ENHl) {
  __shared__ float WL[NF * 16];
  int bb = blockIdx.x / TT, t = blockIdx.x - bb * TT;
  for (int i = threadIdx.x; i < NF * 16; i += 320) WL[i] = WV[(long)bb * NF * 16 + i];
  __syncthreads();
  int f = threadIdx.x;
  long base = ((long)bb * TT + t) * KPAD;
  if (f < NF) {
    float er = 0.f, ei = 0.f;
#pragma unroll
    for (int c = 0; c < 8; c++) {
      float wr = WL[(f * 8 + c) * 2], wi = WL[(f * 8 + c) * 2 + 1];
      const float* srow = S + (((long)(bb * 8 + c) * TT) + t) * DD;
      float sr = srow[f], si = srow[NF + f];
      er += wr * sr + wi * si;
      ei += wr * si - wi * sr;
    }
    split_bf16(er, &ENHh[base + f], &ENHl[base + f]);
    split_bf16(ei, &ENHh[base + NF + f], &ENHl[base + NF + f]);
  }
  int z = threadIdx.x - 288;   // threads 288..317 zero the 30 K-pad cols
  if (z >= 0 && z < 30) { ENHh[base + DD + z] = 0; ENHl[base + DD + z] = 0; }
}

// ---------------- overlap-add + normalize + crop ----------------
__global__ void k_ola(const float* __restrict__ IFR, const float* __restrict__ WSQ,
                      float* __restrict__ out) {
  int idx = blockIdx.x * 256 + threadIdx.x;
  if (idx >= NB * LSEQ) return;
  int b = idx / LSEQ, l = idx - b * LSEQ;
  int p = l + FPAD;
  int t0 = (p <= 511) ? 0 : (p - 352) / 160;
  int t1 = p / 160; if (t1 > 600) t1 = 600;
  float s = 0.f;
  for (int t = t0; t <= t1; t++) s += IFR[((long)b * TT + t) * NFFT + (p - t * HOP)];
  out[idx] = s / fmaxf(WSQ[p], 1e-11f);
}

// ---------------- driver ----------------
extern "C" void kernel_launch(void* const* d_in, const int* in_sizes, int n_in,
                              void* d_out, int out_size, void* d_ws, size_t ws_size,
                              hipStream_t stream) {
  (void)in_sizes; (void)n_in; (void)out_size; (void)ws_size;
  const float* x   = (const float*)d_in[0];
  const float* Wih = (const float*)d_in[1];
  const float* Whh = (const float*)d_in[2];
  const float* bih = (const float*)d_in[3];
  const float* bhh = (const float*)d_in[4];
  const float* W1  = (const float*)d_in[5];
  const float* b1  = (const float*)d_in[6];
  const float* W2  = (const float*)d_in[7];
  const float* b2  = (const float*)d_in[8];
  float* ws = (float*)d_ws;

  // XP region: pre-split XPh/XPl; after gemm4 the region is dead -> WF lives there
  // during the LSTM; IFR aliases it later still.
  unsigned short* XPh = (unsigned short*)(ws + 0);            // 6,176,768 ush = 3,088,384 fl
  unsigned short* XPl = (unsigned short*)(ws + 3088384);      // -> region ends 6,176,768 fl
  float* S     = ws + 6176768;    // 19,774,496
  float* XWM   = ws + 25951264;   // 19,774,496 (XW then MS)
  float* HOUT  = ws + 45725760;   // 4,924,288 (pre-GEMM scratch + post-beam ENH split live here too)
  float* PSD_S = ws + 50650048;   // 263,168
  float* PSD_N = ws + 50913216;   // 263,168
  float* WV    = ws + 51176384;   // 32,896
  float* BSUM  = ws + 51209280;   // 512
  float* WSQ   = ws + 51209792;   // 96,512 -> 51,306,304
  unsigned short* W1sh = (unsigned short*)(ws + 51306304);
  unsigned short* W1sl = (unsigned short*)(ws + 51347264);
  unsigned short* W2sh = (unsigned short*)(ws + 51388224);
  unsigned short* W2sl = (unsigned short*)(ws + 51429184); // -> 51,470,144
  unsigned short* WTth = (unsigned short*)(ws + 51470144); // 139,264 fl
  unsigned short* WTtl = (unsigned short*)(ws + 51609408); // -> 51,748,672
  unsigned short* BIth = (unsigned short*)(ws + 51748672); // 139,264 fl
  unsigned short* BItl = (unsigned short*)(ws + 51887936); // -> end 52,027,200 (~208 MB)
  float* MS    = XWM;
  float* IFR   = ws + 0;          // aliases XP region after gemm4
  unsigned short* WF = (unsigned short*)(ws + 0);           // Whh MFMA frags: 262,144 ush = 131,072 fl
  // Pre-GEMM scratch inside HOUT (dead until k_lstm):
  float* BFf = HOUT;                                        // 263,168 fl
  float* BWf = HOUT + 263168;                               // 262,144 fl
  unsigned short* BCh = (unsigned short*)(HOUT + 525312);   // 1152*544 ush = 313,344 fl
  unsigned short* BCl = (unsigned short*)(HOUT + 838656);   // -> 1,152,000 fl < 4,924,288
  // Post-beam ENH split in HOUT (Hout consumed by maskms before k_beam):
  unsigned short* ENHh = (unsigned short*)HOUT;             // 4808*544 ush = 1,307,776 fl
  unsigned short* ENHl = (unsigned short*)(HOUT + 1307776);

  k_wsq<<<(XPLEN + 255) / 256, 256, 0, stream>>>(WSQ);
  k_bff<<<(NFFT * DD + 255) / 256, 256, 0, stream>>>(BFf);
  k_wtsplit<<<(G4 * KPAD + 255) / 256, 256, 0, stream>>>(Wih, WTth, WTtl);
  k_bisplit<<<(NFFT * KPAD + 255) / 256, 256, 0, stream>>>(BIth, BItl);
  k_bsum<<<2, 256, 0, stream>>>(bih, bhh, BSUM);
  k_wmsplit<<<(2 * 640 * HH + 255) / 256, 256, 0, stream>>>(W1, W2, W1sh, W1sl, W2sh, W2sl);
  k_xp<<<(NSEQ * XPLEN + 255) / 256, 256, 0, stream>>>(x, XPh, XPl);

  // BW = BF @ Wih^T  (512x512, K=514) — small gemm3
  {
    dim3 g(4, 4);
    k_gemm3<0><<<g, 256, 0, stream>>>(BFf, WTth, WTtl, nullptr, BWf, 512, 512, DD, DD, G4);
  }
  // combined split B = [BF | BW]
  k_bcomb<<<(1152 * KPAD + 255) / 256, 256, 0, stream>>>(BWf, BCh, BCl);

  // fused STFT + xW: S[38464,514] and XW[38464,512(permuted)] in one gather-GEMM
  {
    dim3 g(9, 301);
    k_gemm4<<<g, 256, 0, stream>>>(XPh, XPl, BCh, BCl, BSUM, S, XWM);
  }

  // Whh fragments into the now-dead XP region, then the batched-MFMA LSTM
  k_wfrag<<<512, 256, 0, stream>>>(Whh, WF);
  k_lstm<<<4, 512, 0, stream>>>(XWM, WF, HOUT);

  dim3 gm(9, 601);
  k_maskms<<<gm, 256, 0, stream>>>(HOUT, W1sh, W1sl, b1, S, MS);
  k_psd<<<NB * NF, 256, 0, stream>>>(MS, PSD_S);
  k_maskms<<<gm, 256, 0, stream>>>(HOUT, W2sh, W2sl, b2, S, MS);
  k_psd<<<NB * NF, 256, 0, stream>>>(MS, PSD_N);

  k_solve<<<(NB * NF + 63) / 64, 64, 0, stream>>>(PSD_S, PSD_N, WV);
  k_beam<<<NB * TT, 320, 0, stream>>>(S, WV, ENHh, ENHl);

  // iSTFT: IFR[4808,512] = ENH @ BI (pre-split A)
  {
    dim3 g(4, 38);
    k_gemm5<<<g, 256, 0, stream>>>(ENHh, ENHl, BIth, BItl, IFR, NB * TT, NFFT, NFFT);
  }

  k_ola<<<(NB * LSEQ + 255) / 256, 256, 0, stream>>>(IFR, WSQ, (float*)d_out);
}

// Round 3
// 1160.062 us; speedup vs baseline: 1.5941x; 1.5941x over previous
//
#include <hip/hip_runtime.h>
#include <math.h>

#define NFFT  512
#define WINL  320
#define HOP   160
#define FPAD  256
#define NF    257
#define TT    601
#define LSEQ  96000
#define XPLEN 96512
#define NCH   8
#define NB    8
#define NSEQ  64
#define NROWS 38464   // NSEQ*TT
#define DD    514
#define HH    128
#define G4    512
#define KPAD  544     // 17*32, zero-padded K for split-B arrays
#define NCOMB 1026    // 514 (S cols) + 512 (XW cols)

typedef _Float16 h2v __attribute__((ext_vector_type(2)));
typedef short bf16x8 __attribute__((ext_vector_type(8)));
typedef float f32x4 __attribute__((ext_vector_type(4)));

// ---------------- init helpers ----------------
__device__ __forceinline__ float winval(int k) {
  if (k < 96 || k >= 416) return 0.f;
  return 0.5f - 0.5f * cosf((float)(2.0 * M_PI / 320.0) * (float)(k - 96));
}

__device__ __forceinline__ void split_bf16(float v, unsigned short* h, unsigned short* l) {
  unsigned int hb = __float_as_uint(v) >> 16;
  float r = v - __uint_as_float(hb << 16);
  *h = (unsigned short)hb;
  *l = (unsigned short)(__float_as_uint(r) >> 16);
}

__global__ void k_wsq(float* __restrict__ wsq) {
  int p = blockIdx.x * 256 + threadIdx.x;
  if (p >= XPLEN) return;
  int t0 = (p <= 511) ? 0 : (p - 352) / 160;
  int t1 = p / 160; if (t1 > 600) t1 = 600;
  float s = 0.f;
  for (int t = t0; t <= t1; t++) { float w = winval(p - t * HOP); s += w * w; }
  wsq[p] = s;
}

// fp32 forward-DFT matrix BFf[k][d] (512 x 514), for the BW precompute GEMM
__global__ void k_bff(float* __restrict__ BFf) {
  int idx = blockIdx.x * 256 + threadIdx.x;
  if (idx >= NFFT * DD) return;
  int k = idx / DD, d = idx - k * DD;
  float w = winval(k);
  int f = (d < NF) ? d : d - NF;
  int m = (k * f) & 511;
  float th = (float)(M_PI / 256.0) * (float)m;
  BFf[idx] = ((d < NF) ? cosf(th) : -sinf(th)) * w;
}

// WT split: Bt[n][k] = Wih[n][k]  (used by the BW precompute)
__global__ void k_wtsplit(const float* __restrict__ Wih, unsigned short* __restrict__ H,
                          unsigned short* __restrict__ L) {
  int idx = blockIdx.x * 256 + threadIdx.x;
  if (idx >= G4 * KPAD) return;
  int n = idx / KPAD, k = idx - n * KPAD;
  float v = (k < DD) ? Wih[n * DD + k] : 0.f;
  split_bf16(v, &H[idx], &L[idx]);
}

// Combined split B for the fused STFT+xW GEMM: BC[n][k], n in [0,1152)
__global__ void k_bcomb(const float* __restrict__ BWf, unsigned short* __restrict__ H,
                        unsigned short* __restrict__ L) {
  int idx = blockIdx.x * 256 + threadIdx.x;
  if (idx >= 1152 * KPAD) return;
  int n = idx / KPAD, k = idx - n * KPAD;
  float v = 0.f;
  if (k < NFFT) {
    if (n < DD) {
      float w = winval(k);
      int f = (n < NF) ? n : n - NF;
      int m = (k * f) & 511;
      float th = (float)(M_PI / 256.0) * (float)m;
      v = ((n < NF) ? cosf(th) : -sinf(th)) * w;
    } else if (n < NCOMB) {
      v = BWf[k * G4 + (n - 514)];
    }
  }
  split_bf16(v, &H[idx], &L[idx]);
}

// BI split: Bt[n][kk] = BI[kk][n]
__global__ void k_bisplit(unsigned short* __restrict__ H, unsigned short* __restrict__ L) {
  int idx = blockIdx.x * 256 + threadIdx.x;
  if (idx >= NFFT * KPAD) return;
  int n = idx / KPAD, kk = idx - n * KPAD;
  float v = 0.f;
  if (kk < DD) {
    float w = winval(n);
    int f = (kk < NF) ? kk : kk - NF;
    int edge = (f == 0 || f == 256);
    float alpha = edge ? 1.f : 2.f;
    int m = (n * f) & 511;
    float th = (float)(M_PI / 256.0) * (float)m;
    float c;
    if (kk < NF) c = alpha * cosf(th);
    else         c = edge ? 0.f : -alpha * sinf(th);
    v = c * w * (1.f / 512.f);
  }
  split_bf16(v, &H[idx], &L[idx]);
}

__global__ void k_bsum(const float* __restrict__ bih, const float* __restrict__ bhh,
                       float* __restrict__ BSUM) {
  int idx = blockIdx.x * 256 + threadIdx.x;
  if (idx < G4) BSUM[idx] = bih[idx] + bhh[idx];
}

// W1/W2 mask-weight split: Ws[n'][k], n' = ri*320 + f
__global__ void k_wmsplit(const float* __restrict__ W1, const float* __restrict__ W2,
                          unsigned short* __restrict__ W1h, unsigned short* __restrict__ W1l,
                          unsigned short* __restrict__ W2h, unsigned short* __restrict__ W2l) {
  int idx = blockIdx.x * 256 + threadIdx.x;
  if (idx >= 2 * 640 * HH) return;
  int m = idx / (640 * HH);
  int rem = idx - m * 640 * HH;
  int np = rem / HH, k = rem - np * HH;
  int ri = np / 320, f = np - ri * 320;
  float v = 0.f;
  if (f < NF) {
    int fcol = (ri == 0) ? f : NF + f;
    v = (m == 0) ? W1[fcol * HH + k] : W2[fcol * HH + k];
  }
  unsigned short h, l;
  split_bf16(v, &h, &l);
  if (m == 0) { W1h[rem] = h; W1l[rem] = l; }
  else        { W2h[rem] = h; W2l[rem] = l; }
}

// pack Whh into f16 pairs, uint4-transposed (v8 layout, no permute)
__global__ void k_wpack(const float* __restrict__ Whh, unsigned int* __restrict__ WhhP4) {
  int idx = blockIdx.x * 256 + threadIdx.x;
  if (idx >= G4 * 64) return;
  int j = idx >> 6, k2 = idx & 63;
  _Float16 lo = (_Float16)Whh[j * HH + 2 * k2];
  _Float16 hi = (_Float16)Whh[j * HH + 2 * k2 + 1];
  unsigned int u = ((unsigned int)__builtin_bit_cast(unsigned short, hi) << 16)
                 |  (unsigned int)__builtin_bit_cast(unsigned short, lo);
  WhhP4[(k2 >> 2) * (G4 * 4) + j * 4 + (k2 & 3)] = u;
}

// reflect-padded multichannel extraction, pre-split to bf16 hi/lo: XPh/XPl[n][i]
__global__ void k_xp(const float* __restrict__ x, unsigned short* __restrict__ XPh,
                     unsigned short* __restrict__ XPl) {
  int idx = blockIdx.x * 256 + threadIdx.x;
  if (idx >= NSEQ * XPLEN) return;
  int n = idx / XPLEN, i = idx - n * XPLEN;
  int j = i - FPAD;
  if (j < 0) j = -j;
  else if (j >= LSEQ) j = 2 * LSEQ - 2 - j;
  int b = n >> 3, c = n & 7;
  float v = x[((long)b * LSEQ + j) * NCH + c];
  split_bf16(v, &XPh[idx], &XPl[idx]);
}

// ---------------- split-bf16 MFMA GEMM (fp32 A): C[M,N] = A[M,K] * Bt^T (+bias) ----------------
template <int GATHER>
__launch_bounds__(256)
__global__ void k_gemm3(const float* __restrict__ A,
                        const unsigned short* __restrict__ Bth,
                        const unsigned short* __restrict__ Btl,
                        const float* __restrict__ bias, float* __restrict__ C,
                        int M, int N, int K, int lda, int ldc) {
  __shared__ __align__(16) unsigned short sAh[128 * 40];
  __shared__ __align__(16) unsigned short sAl[128 * 40];
  __shared__ __align__(16) unsigned short sBh[128 * 40];
  __shared__ __align__(16) unsigned short sBl[128 * 40];
  const int tid = threadIdx.x;
  const int row0 = blockIdx.y * 128, col0 = blockIdx.x * 128;
  const int sar = tid >> 1, sak = (tid & 1) * 16;
  const int arow = row0 + sar;
  long abase = (long)arow * lda;
  const bool arok = (arow < M);
  const int lane = tid & 63, w = tid >> 6;
  const int wm = (w >> 1) * 64, wn = (w & 1) * 64;
  const int l15 = lane & 15, quad = lane >> 4;
  f32x4 acc[4][4] = {};
  unsigned int* aH = (unsigned int*)sAh;
  unsigned int* aL = (unsigned int*)sAl;
  uint4* bH = (uint4*)sBh;
  uint4* bL = (uint4*)sBl;
  for (int k0 = 0; k0 < K; k0 += 32) {
#pragma unroll
    for (int i = 0; i < 8; i++) {
      int kk = k0 + sak + 2 * i;
      float v0 = 0.f, v1 = 0.f;
      if (arok) {
        if (kk + 1 < K) { float2 t2 = *(const float2*)(A + abase + kk); v0 = t2.x; v1 = t2.y; }
        else if (kk < K) { v0 = A[abase + kk]; }
      }
      unsigned int h0 = __float_as_uint(v0) >> 16, h1 = __float_as_uint(v1) >> 16;
      float r0 = v0 - __uint_as_float(h0 << 16), r1 = v1 - __uint_as_float(h1 << 16);
      unsigned int l0 = __float_as_uint(r0) >> 16, l1 = __float_as_uint(r1) >> 16;
      aH[sar * 20 + (sak >> 1) + i] = h0 | (h1 << 16);
      aL[sar * 20 + (sak >> 1) + i] = l0 | (l1 << 16);
    }
#pragma unroll
    for (int h = 0; h < 2; h++) {
      int idx = tid + h * 256;
      int r = idx >> 2, c = idx & 3;
      long go = (long)(col0 + r) * KPAD + k0 + c * 8;
      bH[r * 5 + c] = *(const uint4*)(Bth + go);
      bL[r * 5 + c] = *(const uint4*)(Btl + go);
    }
    __syncthreads();
    bf16x8 ah[4], al[4], bh[4], bl[4];
#pragma unroll
    for (int i = 0; i < 4; i++) {
      int off = (wm + i * 16 + l15) * 40 + quad * 8;
      ah[i] = *(const bf16x8*)(sAh + off);
      al[i] = *(const bf16x8*)(sAl + off);
      int boff = (wn + i * 16 + l15) * 40 + quad * 8;
      bh[i] = *(const bf16x8*)(sBh + boff);
      bl[i] = *(const bf16x8*)(sBl + boff);
    }
#pragma unroll
    for (int i = 0; i < 4; i++)
#pragma unroll
      for (int j = 0; j < 4; j++) {
        acc[i][j] = __builtin_amdgcn_mfma_f32_16x16x32_bf16(al[i], bh[j], acc[i][j], 0, 0, 0);
        acc[i][j] = __builtin_amdgcn_mfma_f32_16x16x32_bf16(ah[i], bl[j], acc[i][j], 0, 0, 0);
        acc[i][j] = __builtin_amdgcn_mfma_f32_16x16x32_bf16(ah[i], bh[j], acc[i][j], 0, 0, 0);
      }
    __syncthreads();
  }
#pragma unroll
  for (int i = 0; i < 4; i++)
#pragma unroll
    for (int j = 0; j < 4; j++) {
      int cc = col0 + wn + j * 16 + l15;
      if (cc >= N) continue;
      float bv = bias ? bias[cc] : 0.f;
#pragma unroll
      for (int rg = 0; rg < 4; rg++) {
        int rr = row0 + wm + i * 16 + quad * 4 + rg;
        if (rr < M) C[(long)rr * ldc + cc] = acc[i][j][rg] + bv;
      }
    }
}

// ---------------- fused STFT+xW GEMM: pre-split A (gathered XP), combined B ----------------
// C[38464, 1026]: cols <514 -> S; cols 514..1025 -> XW (+bsum). K=512, tile 128x128.
__launch_bounds__(256)
__global__ void k_gemm4(const unsigned short* __restrict__ Ah, const unsigned short* __restrict__ Al,
                        const unsigned short* __restrict__ Bh, const unsigned short* __restrict__ Bl,
                        const float* __restrict__ bsum, float* __restrict__ S,
                        float* __restrict__ XW) {
  __shared__ __align__(16) unsigned short sAh[128 * 40];
  __shared__ __align__(16) unsigned short sAl[128 * 40];
  __shared__ __align__(16) unsigned short sBh[128 * 40];
  __shared__ __align__(16) unsigned short sBl[128 * 40];
  const int tid = threadIdx.x;
  const int row0 = blockIdx.y * 128, col0 = blockIdx.x * 128;
  const int sr0 = tid >> 2, c4 = (tid & 3) * 8, cq = tid & 3;
  long ab0, ab1;
  { int rr = row0 + sr0;      int n = rr / TT, t = rr - n * TT; ab0 = (long)n * XPLEN + (long)t * HOP; }
  { int rr = row0 + sr0 + 64; int n = rr / TT, t = rr - n * TT; ab1 = (long)n * XPLEN + (long)t * HOP; }
  const int lane = tid & 63, w = tid >> 6;
  const int wm = (w >> 1) * 64, wn = (w & 1) * 64;
  const int l15 = lane & 15, quad = lane >> 4;
  f32x4 acc[4][4] = {};
  uint4* aH4 = (uint4*)sAh; uint4* aL4 = (uint4*)sAl;
  uint4* bH4 = (uint4*)sBh; uint4* bL4 = (uint4*)sBl;
  for (int k0 = 0; k0 < NFFT; k0 += 32) {
    aH4[sr0 * 5 + cq]        = *(const uint4*)(Ah + ab0 + k0 + c4);
    aL4[sr0 * 5 + cq]        = *(const uint4*)(Al + ab0 + k0 + c4);
    aH4[(sr0 + 64) * 5 + cq] = *(const uint4*)(Ah + ab1 + k0 + c4);
    aL4[(sr0 + 64) * 5 + cq] = *(const uint4*)(Al + ab1 + k0 + c4);
    {
      long go = (long)(col0 + sr0) * KPAD + k0 + c4;
      bH4[sr0 * 5 + cq] = *(const uint4*)(Bh + go);
      bL4[sr0 * 5 + cq] = *(const uint4*)(Bl + go);
      go = (long)(col0 + sr0 + 64) * KPAD + k0 + c4;
      bH4[(sr0 + 64) * 5 + cq] = *(const uint4*)(Bh + go);
      bL4[(sr0 + 64) * 5 + cq] = *(const uint4*)(Bl + go);
    }
    __syncthreads();
    bf16x8 ah[4], al[4], bh[4], bl[4];
#pragma unroll
    for (int i = 0; i < 4; i++) {
      int off = (wm + i * 16 + l15) * 40 + quad * 8;
      ah[i] = *(const bf16x8*)(sAh + off);
      al[i] = *(const bf16x8*)(sAl + off);
      int boff = (wn + i * 16 + l15) * 40 + quad * 8;
      bh[i] = *(const bf16x8*)(sBh + boff);
      bl[i] = *(const bf16x8*)(sBl + boff);
    }
#pragma unroll
    for (int i = 0; i < 4; i++)
#pragma unroll
      for (int j = 0; j < 4; j++) {
        acc[i][j] = __builtin_amdgcn_mfma_f32_16x16x32_bf16(al[i], bh[j], acc[i][j], 0, 0, 0);
        acc[i][j] = __builtin_amdgcn_mfma_f32_16x16x32_bf16(ah[i], bl[j], acc[i][j], 0, 0, 0);
        acc[i][j] = __builtin_amdgcn_mfma_f32_16x16x32_bf16(ah[i], bh[j], acc[i][j], 0, 0, 0);
      }
    __syncthreads();
  }
#pragma unroll
  for (int i = 0; i < 4; i++)
#pragma unroll
    for (int j = 0; j < 4; j++) {
      int cc = col0 + wn + j * 16 + l15;
      if (cc >= NCOMB) continue;
#pragma unroll
      for (int rg = 0; rg < 4; rg++) {
        int rr = row0 + wm + i * 16 + quad * 4 + rg;
        if (rr >= NROWS) continue;
        float v = acc[i][j][rg];
        if (cc < DD) S[(long)rr * DD + cc] = v;
        else         XW[(long)rr * G4 + (cc - 514)] = v + bsum[cc - 514];
      }
    }
}

// ---------------- iSTFT GEMM: pre-split A (pitch KPAD), B = BI split ----------------
__launch_bounds__(256)
__global__ void k_gemm5(const unsigned short* __restrict__ Ah, const unsigned short* __restrict__ Al,
                        const unsigned short* __restrict__ Bh, const unsigned short* __restrict__ Bl,
                        float* __restrict__ C, int M, int N, int ldc) {
  __shared__ __align__(16) unsigned short sAh[128 * 40];
  __shared__ __align__(16) unsigned short sAl[128 * 40];
  __shared__ __align__(16) unsigned short sBh[128 * 40];
  __shared__ __align__(16) unsigned short sBl[128 * 40];
  const int tid = threadIdx.x;
  const int row0 = blockIdx.y * 128, col0 = blockIdx.x * 128;
  const int sr0 = tid >> 2, c4 = (tid & 3) * 8, cq = tid & 3;
  const int lane = tid & 63, w = tid >> 6;
  const int wm = (w >> 1) * 64, wn = (w & 1) * 64;
  const int l15 = lane & 15, quad = lane >> 4;
  f32x4 acc[4][4] = {};
  uint4* aH4 = (uint4*)sAh; uint4* aL4 = (uint4*)sAl;
  uint4* bH4 = (uint4*)sBh; uint4* bL4 = (uint4*)sBl;
  for (int k0 = 0; k0 < KPAD; k0 += 32) {
    {
      long go = (long)(row0 + sr0) * KPAD + k0 + c4;
      aH4[sr0 * 5 + cq] = *(const uint4*)(Ah + go);
      aL4[sr0 * 5 + cq] = *(const uint4*)(Al + go);
      go = (long)(row0 + sr0 + 64) * KPAD + k0 + c4;
      aH4[(sr0 + 64) * 5 + cq] = *(const uint4*)(Ah + go);
      aL4[(sr0 + 64) * 5 + cq] = *(const uint4*)(Al + go);
    }
    {
      long go = (long)(col0 + sr0) * KPAD + k0 + c4;
      bH4[sr0 * 5 + cq] = *(const uint4*)(Bh + go);
      bL4[sr0 * 5 + cq] = *(const uint4*)(Bl + go);
      go = (long)(col0 + sr0 + 64) * KPAD + k0 + c4;
      bH4[(sr0 + 64) * 5 + cq] = *(const uint4*)(Bh + go);
      bL4[(sr0 + 64) * 5 + cq] = *(const uint4*)(Bl + go);
    }
    __syncthreads();
    bf16x8 ah[4], al[4], bh[4], bl[4];
#pragma unroll
    for (int i = 0; i < 4; i++) {
      int off = (wm + i * 16 + l15) * 40 + quad * 8;
      ah[i] = *(const bf16x8*)(sAh + off);
      al[i] = *(const bf16x8*)(sAl + off);
      int boff = (wn + i * 16 + l15) * 40 + quad * 8;
      bh[i] = *(const bf16x8*)(sBh + boff);
      bl[i] = *(const bf16x8*)(sBl + boff);
    }
#pragma unroll
    for (int i = 0; i < 4; i++)
#pragma unroll
      for (int j = 0; j < 4; j++) {
        acc[i][j] = __builtin_amdgcn_mfma_f32_16x16x32_bf16(al[i], bh[j], acc[i][j], 0, 0, 0);
        acc[i][j] = __builtin_amdgcn_mfma_f32_16x16x32_bf16(ah[i], bl[j], acc[i][j], 0, 0, 0);
        acc[i][j] = __builtin_amdgcn_mfma_f32_16x16x32_bf16(ah[i], bh[j], acc[i][j], 0, 0, 0);
      }
    __syncthreads();
  }
#pragma unroll
  for (int i = 0; i < 4; i++)
#pragma unroll
    for (int j = 0; j < 4; j++) {
      int cc = col0 + wn + j * 16 + l15;
      if (cc >= N) continue;
#pragma unroll
      for (int rg = 0; rg < 4; rg++) {
        int rr = row0 + wm + i * 16 + quad * 4 + rg;
        if (rr < M) C[(long)rr * ldc + cc] = acc[i][j][rg];
      }
    }
}

// ---------------- LSTM v11: v8 structure + 3 stall removals ----------------
// (a) raw s_barrier with lgkmcnt-only drain (no vmcnt(0) -> XW prefetch and Hout
//     stores stay in flight across barriers)
// (b) h broadcast via uniform ds_read_b128 (LDS pipe) instead of 64 v_readlane
//     (VALU) -> dot-phase VALU halved; accumulation pairing identical to v8
// (c) distributed nonlinearity: each thread applies its own gate's sigma/tanh
//     (wave-uniform branch) before gl[] write; tail (j<128) is 1 tanh + 3 ops
__device__ __forceinline__ float tanh_fast(float x) {
  float e = __expf(2.f * x);
  return 1.f - 2.f / (e + 1.f);
}

__launch_bounds__(512, 2)
__global__ void k_lstm(const float* __restrict__ XW, const unsigned int* __restrict__ WhhP4,
                       float* __restrict__ Hout) {
  __shared__ __align__(16) unsigned int hl2[64];
  __shared__ float gl[G4];
  const int j = threadIdx.x;
  const int n = blockIdx.x;
  const uint4* W4 = (const uint4*)WhhP4;
  unsigned int wp[64];
#pragma unroll
  for (int i4 = 0; i4 < 16; i4++) {
    uint4 v = W4[i4 * G4 + j];
    wp[4 * i4]     = v.x;
    wp[4 * i4 + 1] = v.y;
    wp[4 * i4 + 2] = v.z;
    wp[4 * i4 + 3] = v.w;
  }
  float cst = 0.f;
  if (j < 64) hl2[j] = 0u;
  const float* xwrow = XW + (long)n * TT * G4 + j;
  float xnext = xwrow[0];
  const uint4* h4 = (const uint4*)hl2;
  const bool isg = (j >= 2 * HH) && (j < 3 * HH);   // 'g' gate rows -> tanh, else sigmoid
  __syncthreads();
  for (int t = 0; t < TT; t++) {
    float xv = xnext;
    if (t + 1 < TT) xnext = xwrow[(long)(t + 1) * G4];
    float a0 = 0.f, a1 = 0.f, a2 = 0.f, a3 = 0.f;
#pragma unroll
    for (int k = 0; k < 16; k++) {
      uint4 hv4 = h4[k];   // uniform address -> LDS broadcast, conflict-free
      a0 = __builtin_amdgcn_fdot2(__builtin_bit_cast(h2v, hv4.x), __builtin_bit_cast(h2v, wp[4 * k]),     a0, false);
      a1 = __builtin_amdgcn_fdot2(__builtin_bit_cast(h2v, hv4.y), __builtin_bit_cast(h2v, wp[4 * k + 1]), a1, false);
      a2 = __builtin_amdgcn_fdot2(__builtin_bit_cast(h2v, hv4.z), __builtin_bit_cast(h2v, wp[4 * k + 2]), a2, false);
      a3 = __builtin_amdgcn_fdot2(__builtin_bit_cast(h2v, hv4.w), __builtin_bit_cast(h2v, wp[4 * k + 3]), a3, false);
    }
    float a = ((a0 + a1) + (a2 + a3)) + xv;
    float nl;
    if (isg) nl = tanh_fast(a);
    else     nl = 1.f / (1.f + __expf(-a));
    gl[j] = nl;
    asm volatile("s_waitcnt lgkmcnt(0)" ::: "memory");
    __builtin_amdgcn_s_barrier();
    if (j < HH) {
      float ni = gl[j], nf = gl[HH + j], ng = gl[2 * HH + j], no = gl[3 * HH + j];
      cst = nf * cst + ni * ng;
      float hv = no * tanh_fast(cst);
      ((_Float16*)hl2)[j] = (_Float16)hv;
      Hout[((long)n * TT + t) * HH + j] = hv;
    }
    asm volatile("s_waitcnt lgkmcnt(0)" ::: "memory");
    __builtin_amdgcn_s_barrier();
  }
}

// ---------------- mask GEMM (split-bf16 MFMA) + mask apply + transpose ----------------
// MS layout: [b][f][c][t] complex-interleaved (re,im)
__launch_bounds__(256)
__global__ void k_maskms(const float* __restrict__ Hout,
                         const unsigned short* __restrict__ Wsh,
                         const unsigned short* __restrict__ Wsl,
                         const float* __restrict__ bias, const float* __restrict__ S,
                         float* __restrict__ MS) {
  __shared__ __align__(16) unsigned short sAh[64 * 40];
  __shared__ __align__(16) unsigned short sAl[64 * 40];
  __shared__ __align__(16) unsigned short sBh[64 * 40];
  __shared__ __align__(16) unsigned short sBl[64 * 40];
  __shared__ float Cs[64][68];
  __shared__ float SR[64][33];
  __shared__ float SI[64][33];
  const int tid = threadIdx.x;
  const int f0 = blockIdx.x * 32;
  const int row0 = blockIdx.y * 64;
  const int lane = tid & 63, w = tid >> 6;
  const int wm = w * 16;
  const int l15 = lane & 15, quad = lane >> 4;
  const int sar = tid >> 2;
  const int sak = (tid & 3) * 8;
  const int np = ((sar < 32) ? 0 : 320 - 32) + f0 + sar;
  unsigned int* aH = (unsigned int*)sAh;
  unsigned int* aL = (unsigned int*)sAl;
  f32x4 acc[4] = {};
  for (int k0 = 0; k0 < HH; k0 += 32) {
    {
      const float* ap = Hout + (long)(row0 + sar) * HH + k0 + sak;
      float4 v0 = *(const float4*)ap;
      float4 v1 = *(const float4*)(ap + 4);
      float vv[8] = {v0.x, v0.y, v0.z, v0.w, v1.x, v1.y, v1.z, v1.w};
#pragma unroll
      for (int i = 0; i < 4; i++) {
        unsigned int h0 = __float_as_uint(vv[2 * i]) >> 16, h1 = __float_as_uint(vv[2 * i + 1]) >> 16;
        float r0 = vv[2 * i] - __uint_as_float(h0 << 16), r1 = vv[2 * i + 1] - __uint_as_float(h1 << 16);
        unsigned int l0 = __float_as_uint(r0) >> 16, l1 = __float_as_uint(r1) >> 16;
        aH[sar * 20 + (sak >> 1) + i] = h0 | (h1 << 16);
        aL[sar * 20 + (sak >> 1) + i] = l0 | (l1 << 16);
      }
    }
    {
      long go = (long)np * HH + k0 + sak;
      *(uint4*)(sBh + sar * 40 + sak) = *(const uint4*)(Wsh + go);
      *(uint4*)(sBl + sar * 40 + sak) = *(const uint4*)(Wsl + go);
    }
    __syncthreads();
    bf16x8 ah = *(const bf16x8*)(sAh + (wm + l15) * 40 + quad * 8);
    bf16x8 al = *(const bf16x8*)(sAl + (wm + l15) * 40 + quad * 8);
#pragma unroll
    for (int ct = 0; ct < 4; ct++) {
      bf16x8 bh = *(const bf16x8*)(sBh + (ct * 16 + l15) * 40 + quad * 8);
      bf16x8 bl = *(const bf16x8*)(sBl + (ct * 16 + l15) * 40 + quad * 8);
      acc[ct] = __builtin_amdgcn_mfma_f32_16x16x32_bf16(al, bh, acc[ct], 0, 0, 0);
      acc[ct] = __builtin_amdgcn_mfma_f32_16x16x32_bf16(ah, bl, acc[ct], 0, 0, 0);
      acc[ct] = __builtin_amdgcn_mfma_f32_16x16x32_bf16(ah, bh, acc[ct], 0, 0, 0);
    }
    __syncthreads();
  }
#pragma unroll
  for (int ct = 0; ct < 4; ct++) {
    int col = ct * 16 + l15;
    int f = f0 + (col & 31);
    int fcol = (col < 32) ? f : NF + f;
    float bv = (f < NF) ? bias[fcol] : 0.f;
#pragma unroll
    for (int rg = 0; rg < 4; rg++) Cs[wm + quad * 4 + rg][col] = acc[ct][rg] + bv;
  }
  __syncthreads();
  {
    int fl = tid & 31, r8 = tid >> 5;
    int f = f0 + fl;
#pragma unroll
    for (int i = 0; i < 8; i++) {
      int rl = r8 * 8 + i;
      int rr = row0 + rl;
      float rm = Cs[rl][fl], im = Cs[rl][32 + fl];
      float sr = 0.f, si = 0.f;
      if (f < NF) { sr = S[(long)rr * DD + f]; si = S[(long)rr * DD + NF + f]; }
      SR[rl][fl] = rm * sr - im * si;
      SI[rl][fl] = rm * si + im * sr;
    }
  }
  __syncthreads();
  {
    int tl = tid & 63, fq = tid >> 6;
    int rr = row0 + tl;
    int n = rr / TT, t = rr - n * TT;
    int b = n >> 3, c = n & 7;
#pragma unroll
    for (int i = 0; i < 8; i++) {
      int fl = fq * 8 + i;
      int f = f0 + fl;
      if (f < NF) {
        long addr = ((((long)b * NF + f) * 8 + c) * (long)TT + t) * 2;
        *(float2*)&MS[addr] = make_float2(SR[tl][fl], SI[tl][fl]);
      }
    }
  }
}

// ---------------- PSD: one block per (b,f); complex-interleaved MS ----------------
__launch_bounds__(256)
__global__ void k_psd(const float* __restrict__ MS, float* __restrict__ PSD) {
  __shared__ float buf[9616];
  __shared__ float part[64][8];
  const int tid = threadIdx.x;
  const long base = (long)blockIdx.x * 9616;
  for (int i = tid; i < 9616; i += 256) buf[i] = MS[base + i];
  __syncthreads();
  int p = tid & 63, q = tid >> 6;
  int c = p >> 3, e = p & 7;
  const float2* xc = (const float2*)&buf[c * 1202];
  const float2* xe = (const float2*)&buf[e * 1202];
  int t0 = q * 150, t1 = (q == 3) ? TT : t0 + 150;
  float ar = 0.f, ai = 0.f;
  for (int t = t0; t < t1; t++) {
    float2 m = xc[t];
    float2 v = xe[t];
    ar += m.x * v.x + m.y * v.y;
    ai += m.y * v.x - m.x * v.y;
  }
  part[p][q * 2] = ar; part[p][q * 2 + 1] = ai;
  __syncthreads();
  if (tid < 64) {
    float sr = part[tid][0] + part[tid][2] + part[tid][4] + part[tid][6];
    float si = part[tid][1] + part[tid][3] + part[tid][5] + part[tid][7];
    PSD[((long)blockIdx.x * 64 + tid) * 2]     = sr * (1.f / 601.f);
    PSD[((long)blockIdx.x * 64 + tid) * 2 + 1] = si * (1.f / 601.f);
  }
}

// ---------------- 8x8 complex solve + MVDR weight ----------------
__launch_bounds__(64)
__global__ void k_solve(const float* __restrict__ PS, const float* __restrict__ PN,
                        float* __restrict__ WV) {
  int idx = blockIdx.x * 64 + threadIdx.x;
  if (idx >= NB * NF) return;
  float Ar[8][8], Ai[8][8], Br[8][8], Bi[8][8];
  const float* pn = PN + (long)idx * 128;
  const float* ps = PS + (long)idx * 128;
  for (int i = 0; i < 8; i++)
    for (int j = 0; j < 8; j++) {
      Ar[i][j] = pn[(i * 8 + j) * 2]; Ai[i][j] = pn[(i * 8 + j) * 2 + 1];
      Br[i][j] = ps[(i * 8 + j) * 2]; Bi[i][j] = ps[(i * 8 + j) * 2 + 1];
    }
  float tr = 0.f;
  for (int i = 0; i < 8; i++) tr += Ar[i][i];
  float load = 1e-6f * tr / 8.f + 1e-8f;
  for (int i = 0; i < 8; i++) Ar[i][i] += load;
  for (int k = 0; k < 8; k++) {
    int piv = k; float mx = Ar[k][k] * Ar[k][k] + Ai[k][k] * Ai[k][k];
    for (int i = k + 1; i < 8; i++) {
      float m2 = Ar[i][k] * Ar[i][k] + Ai[i][k] * Ai[i][k];
      if (m2 > mx) { mx = m2; piv = i; }
    }
    if (piv != k) {
      for (int j = 0; j < 8; j++) {
        float t0;
        t0 = Ar[k][j]; Ar[k][j] = Ar[piv][j]; Ar[piv][j] = t0;
        t0 = Ai[k][j]; Ai[k][j] = Ai[piv][j]; Ai[piv][j] = t0;
        t0 = Br[k][j]; Br[k][j] = Br[piv][j]; Br[piv][j] = t0;
        t0 = Bi[k][j]; Bi[k][j] = Bi[piv][j]; Bi[piv][j] = t0;
      }
    }
    float dr = Ar[k][k], di = Ai[k][k];
    float inv = 1.f / (dr * dr + di * di);
    float irr = dr * inv, iii = -di * inv;
    for (int j = 0; j < 8; j++) {
      float xr = Ar[k][j], xi = Ai[k][j];
      Ar[k][j] = xr * irr - xi * iii; Ai[k][j] = xr * iii + xi * irr;
      xr = Br[k][j]; xi = Bi[k][j];
      Br[k][j] = xr * irr - xi * iii; Bi[k][j] = xr * iii + xi * irr;
    }
    for (int i = 0; i < 8; i++) {
      if (i == k) continue;
      float fr = Ar[i][k], fi = Ai[i][k];
      for (int j = 0; j < 8; j++) {
        float kr = Ar[k][j], ki = Ai[k][j];
        Ar[i][j] -= fr * kr - fi * ki;
        Ai[i][j] -= fr * ki + fi * kr;
        kr = Br[k][j]; ki = Bi[k][j];
        Br[i][j] -= fr * kr - fi * ki;
        Bi[i][j] -= fr * ki + fi * kr;
      }
    }
  }
  float trr = 1e-8f, tri = 0.f;
  for (int i = 0; i < 8; i++) { trr += Br[i][i]; tri += Bi[i][i]; }
  float inv = 1.f / (trr * trr + tri * tri);
  for (int c = 0; c < 8; c++) {
    float xr = Br[c][0], xi = Bi[c][0];
    WV[((long)idx * 8 + c) * 2]     = (xr * trr + xi * tri) * inv;
    WV[((long)idx * 8 + c) * 2 + 1] = (xi * trr - xr * tri) * inv;
  }
}

// ---------------- beamform -> pre-split ENH (KPAD rows) ----------------
__launch_bounds__(320)
__global__ void k_beam(const float* __restrict__ S, const float* __restrict__ WV,
                       unsigned short* __restrict__ ENHh, unsigned short* __restrict__ ENHl) {
  __shared__ float WL[NF * 16];
  int bb = blockIdx.x / TT, t = blockIdx.x - bb * TT;
  for (int i = threadIdx.x; i < NF * 16; i += 320) WL[i] = WV[(long)bb * NF * 16 + i];
  __syncthreads();
  int f = threadIdx.x;
  long base = ((long)bb * TT + t) * KPAD;
  if (f < NF) {
    float er = 0.f, ei = 0.f;
#pragma unroll
    for (int c = 0; c < 8; c++) {
      float wr = WL[(f * 8 + c) * 2], wi = WL[(f * 8 + c) * 2 + 1];
      const float* srow = S + (((long)(bb * 8 + c) * TT) + t) * DD;
      float sr = srow[f], si = srow[NF + f];
      er += wr * sr + wi * si;
      ei += wr * si - wi * sr;
    }
    split_bf16(er, &ENHh[base + f], &ENHl[base + f]);
    split_bf16(ei, &ENHh[base + NF + f], &ENHl[base + NF + f]);
  }
  int z = threadIdx.x - 288;   // threads 288..317 zero the 30 K-pad cols
  if (z >= 0 && z < 30) { ENHh[base + DD + z] = 0; ENHl[base + DD + z] = 0; }
}

// ---------------- overlap-add + normalize + crop ----------------
__global__ void k_ola(const float* __restrict__ IFR, const float* __restrict__ WSQ,
                      float* __restrict__ out) {
  int idx = blockIdx.x * 256 + threadIdx.x;
  if (idx >= NB * LSEQ) return;
  int b = idx / LSEQ, l = idx - b * LSEQ;
  int p = l + FPAD;
  int t0 = (p <= 511) ? 0 : (p - 352) / 160;
  int t1 = p / 160; if (t1 > 600) t1 = 600;
  float s = 0.f;
  for (int t = t0; t <= t1; t++) s += IFR[((long)b * TT + t) * NFFT + (p - t * HOP)];
  out[idx] = s / fmaxf(WSQ[p], 1e-11f);
}

// ---------------- driver ----------------
extern "C" void kernel_launch(void* const* d_in, const int* in_sizes, int n_in,
                              void* d_out, int out_size, void* d_ws, size_t ws_size,
                              hipStream_t stream) {
  (void)in_sizes; (void)n_in; (void)out_size; (void)ws_size;
  const float* x   = (const float*)d_in[0];
  const float* Wih = (const float*)d_in[1];
  const float* Whh = (const float*)d_in[2];
  const float* bih = (const float*)d_in[3];
  const float* bhh = (const float*)d_in[4];
  const float* W1  = (const float*)d_in[5];
  const float* b1  = (const float*)d_in[6];
  const float* W2  = (const float*)d_in[7];
  const float* b2  = (const float*)d_in[8];
  float* ws = (float*)d_ws;

  // XP region: pre-split XPh/XPl (exactly fills old XP fp32 footprint); IFR aliases later.
  unsigned short* XPh = (unsigned short*)(ws + 0);            // 6,176,768 ush = 3,088,384 fl
  unsigned short* XPl = (unsigned short*)(ws + 3088384);      // -> region ends 6,176,768 fl
  float* S     = ws + 6176768;    // 19,774,496
  float* XWM   = ws + 25951264;   // 19,774,496 (XW then MS; WhhP4 in tail)
  float* HOUT  = ws + 45725760;   // 4,924,288 (pre-GEMM scratch + post-beam ENH split live here too)
  float* PSD_S = ws + 50650048;   // 263,168
  float* PSD_N = ws + 50913216;   // 263,168
  float* WV    = ws + 51176384;   // 32,896
  float* BSUM  = ws + 51209280;   // 512
  float* WSQ   = ws + 51209792;   // 96,512 -> 51,306,304
  unsigned short* W1sh = (unsigned short*)(ws + 51306304);
  unsigned short* W1sl = (unsigned short*)(ws + 51347264);
  unsigned short* W2sh = (unsigned short*)(ws + 51388224);
  unsigned short* W2sl = (unsigned short*)(ws + 51429184); // -> 51,470,144
  unsigned short* WTth = (unsigned short*)(ws + 51470144); // 139,264 fl
  unsigned short* WTtl = (unsigned short*)(ws + 51609408); // -> 51,748,672
  unsigned short* BIth = (unsigned short*)(ws + 51748672); // 139,264 fl
  unsigned short* BItl = (unsigned short*)(ws + 51887936); // -> end 52,027,200 (~208 MB)
  float* MS    = XWM;
  float* IFR   = ws + 0;          // aliases XP region after gemm4
  unsigned int* WhhP4 = (unsigned int*)(XWM + 19693568);   // after true end of XW
  // Pre-GEMM scratch inside HOUT (dead until k_lstm):
  float* BFf = HOUT;                                        // 263,168 fl
  float* BWf = HOUT + 263168;                               // 262,144 fl
  unsigned short* BCh = (unsigned short*)(HOUT + 525312);   // 1152*544 ush = 313,344 fl
  unsigned short* BCl = (unsigned short*)(HOUT + 838656);   // -> 1,152,000 fl < 4,924,288
  // Post-beam ENH split in HOUT (Hout consumed by maskms before k_beam):
  unsigned short* ENHh = (unsigned short*)HOUT;             // 4808*544 ush = 1,307,776 fl
  unsigned short* ENHl = (unsigned short*)(HOUT + 1307776);

  k_wsq<<<(XPLEN + 255) / 256, 256, 0, stream>>>(WSQ);
  k_bff<<<(NFFT * DD + 255) / 256, 256, 0, stream>>>(BFf);
  k_wtsplit<<<(G4 * KPAD + 255) / 256, 256, 0, stream>>>(Wih, WTth, WTtl);
  k_bisplit<<<(NFFT * KPAD + 255) / 256, 256, 0, stream>>>(BIth, BItl);
  k_bsum<<<2, 256, 0, stream>>>(bih, bhh, BSUM);
  k_wmsplit<<<(2 * 640 * HH + 255) / 256, 256, 0, stream>>>(W1, W2, W1sh, W1sl, W2sh, W2sl);
  k_wpack<<<(G4 * 64 + 255) / 256, 256, 0, stream>>>(Whh, WhhP4);
  k_xp<<<(NSEQ * XPLEN + 255) / 256, 256, 0, stream>>>(x, XPh, XPl);

  // BW = BF @ Wih^T  (512x512, K=514) — small gemm3
  {
    dim3 g(4, 4);
    k_gemm3<0><<<g, 256, 0, stream>>>(BFf, WTth, WTtl, nullptr, BWf, 512, 512, DD, DD, G4);
  }
  // combined split B = [BF | BW]
  k_bcomb<<<(1152 * KPAD + 255) / 256, 256, 0, stream>>>(BWf, BCh, BCl);

  // fused STFT + xW: S[38464,514] and XW[38464,512] in one gather-GEMM
  {
    dim3 g(9, 301);
    k_gemm4<<<g, 256, 0, stream>>>(XPh, XPl, BCh, BCl, BSUM, S, XWM);
  }

  k_lstm<<<64, 512, 0, stream>>>(XWM, WhhP4, HOUT);

  dim3 gm(9, 601);
  k_maskms<<<gm, 256, 0, stream>>>(HOUT, W1sh, W1sl, b1, S, MS);
  k_psd<<<NB * NF, 256, 0, stream>>>(MS, PSD_S);
  k_maskms<<<gm, 256, 0, stream>>>(HOUT, W2sh, W2sl, b2, S, MS);
  k_psd<<<NB * NF, 256, 0, stream>>>(MS, PSD_N);

  k_solve<<<(NB * NF + 63) / 64, 64, 0, stream>>>(PSD_S, PSD_N, WV);
  k_beam<<<NB * TT, 320, 0, stream>>>(S, WV, ENHh, ENHl);

  // iSTFT: IFR[4808,512] = ENH @ BI (pre-split A)
  {
    dim3 g(4, 38);
    k_gemm5<<<g, 256, 0, stream>>>(ENHh, ENHl, BIth, BItl, IFR, NB * TT, NFFT, NFFT);
  }

  k_ola<<<(NB * LSEQ + 255) / 256, 256, 0, stream>>>(IFR, WSQ, (float*)d_out);
}